// Round 2
// baseline (1517.927 us; speedup 1.0000x reference)
//
#include <hip/hip_runtime.h>
#include <math.h>

#define N_ 32
#define P_ 16
#define C_ 256
#define S_ 128
#define H_ 4
#define DH_ 64
#define CLS_ 3000

typedef float4 f4;

// ---------------------------------------------------------------------------
// Per-(n,p) grouped GEMM: out[m][s] = sum_k W[m][k] * X[k][s]
// MODE 0: decay  W=decay_w[p] [256][768], X=concat(t_f,t_s,t_l)[n0+n,p] -> t_all (local)
// MODE 1: qkv    W=qkv_w[p]   [768][256], X=t_all (local)              -> qkv (local)
// MODE 2: out    W=out_w[p]   [256][256], X=o (qkv rows 0..255, local)
//                epilogue: +t_all residual, max over s, write wpv^T [p][n0+n][c]
// block 256 threads; tile 64 m x 128 s; thread: 8 m x 4 s
// ---------------------------------------------------------------------------
template<int MODE, int KDIM>
__global__ __launch_bounds__(256) void gemm_np(
    const float* __restrict__ W_all,
    const float* __restrict__ X0,
    const float* __restrict__ X1,
    const float* __restrict__ X2,
    const float* __restrict__ t_all_res,
    float* __restrict__ outp,
    int n0)
{
    __shared__ __align__(16) float Xs[32][128];
    __shared__ float Wst[32][65];

    const int mt = blockIdx.x;
    const int np_l = blockIdx.y;          // local (chunk) np
    const int n_l = np_l >> 4;
    const int p = np_l & 15;
    const int tid = threadIdx.x;
    const int tm = tid >> 5;
    const int ts = tid & 31;
    const int m0 = mt * 64;

    const int MROWS = (MODE == 1) ? 768 : 256;
    const float* Wp = W_all + ((size_t)p * MROWS + m0) * KDIM;

    float acc[8][4];
#pragma unroll
    for (int i = 0; i < 8; ++i)
#pragma unroll
        for (int j = 0; j < 4; ++j) acc[i][j] = 0.f;

    for (int k0 = 0; k0 < KDIM; k0 += 32) {
        const float* Xbase;
        if (MODE == 0) {
            // global input, indexed by global np
            const size_t np_g = (size_t)np_l + (size_t)n0 * P_;
            int t = k0 >> 8;
            const float* src = (t == 0) ? X0 : ((t == 1) ? X1 : X2);
            Xbase = src + (np_g * C_ + (k0 & 255)) * S_;
        } else if (MODE == 1) {
            Xbase = X0 + ((size_t)np_l * C_ + k0) * S_;
        } else {
            Xbase = X0 + ((size_t)np_l * 768 + k0) * S_;
        }
        const f4* xs4 = (const f4*)Xbase;
        f4* xd4 = (f4*)&Xs[0][0];
#pragma unroll
        for (int r = 0; r < 4; ++r) xd4[tid + 256 * r] = xs4[tid + 256 * r];
#pragma unroll
        for (int r = 0; r < 8; ++r) {
            int idx = tid + 256 * r;
            int m = idx >> 5, kk = idx & 31;
            Wst[kk][m] = Wp[(size_t)m * KDIM + k0 + kk];
        }
        __syncthreads();
#pragma unroll
        for (int k = 0; k < 32; ++k) {
            f4 xv = *(const f4*)&Xs[k][ts * 4];
#pragma unroll
            for (int i = 0; i < 8; ++i) {
                float wv = Wst[k][tm * 8 + i];
                acc[i][0] += wv * xv.x;
                acc[i][1] += wv * xv.y;
                acc[i][2] += wv * xv.z;
                acc[i][3] += wv * xv.w;
            }
        }
        __syncthreads();
    }

    if (MODE == 2) {
#pragma unroll
        for (int i = 0; i < 8; ++i) {
            int m = m0 + tm * 8 + i;
            f4 res = *(const f4*)&t_all_res[((size_t)np_l * C_ + m) * S_ + ts * 4];
            float v = fmaxf(fmaxf(acc[i][0] + res.x, acc[i][1] + res.y),
                            fmaxf(acc[i][2] + res.z, acc[i][3] + res.w));
            v = fmaxf(v, __shfl_xor(v, 1));
            v = fmaxf(v, __shfl_xor(v, 2));
            v = fmaxf(v, __shfl_xor(v, 4));
            v = fmaxf(v, __shfl_xor(v, 8));
            v = fmaxf(v, __shfl_xor(v, 16));
            if (ts == 0) outp[((size_t)p * N_ + (n0 + n_l)) * C_ + m] = v;
        }
    } else {
        const int M = MROWS;
#pragma unroll
        for (int i = 0; i < 8; ++i) {
            int m = m0 + tm * 8 + i;
            f4 o;
            o.x = acc[i][0]; o.y = acc[i][1]; o.z = acc[i][2]; o.w = acc[i][3];
            *(f4*)&outp[((size_t)np_l * M + m) * S_ + ts * 4] = o;
        }
    }
}

// ---------------------------------------------------------------------------
// Fused attention per (n,h,p) within chunk. Writes O over q-rows of qkv.
// ---------------------------------------------------------------------------
__global__ __launch_bounds__(256) void attn_kernel(
    const float* __restrict__ qkv,
    float* __restrict__ o_out,      // == qkv base (q rows overwritten)
    int* __restrict__ idx_out,
    int n0)
{
    __shared__ __align__(16) float Qs[64][128];
    __shared__ __align__(16) float Ks[64][128];
    __shared__ __align__(16) float Vs[64][128];
    __shared__ float part[4][128];
    __shared__ float colsum[128];

    const int b = blockIdx.x;
    const int n_l = b / (H_ * P_);
    const int h = (b / P_) % H_;
    const int p = b % P_;
    const int np_l = n_l * P_ + p;
    const int tid = threadIdx.x;

    const float* base = qkv + ((size_t)np_l * 768) * S_;
    {
        const f4* qsrc = (const f4*)(base + (size_t)(h * 64) * S_);
        const f4* ksrc = (const f4*)(base + (size_t)(256 + h * 64) * S_);
        const f4* vsrc = (const f4*)(base + (size_t)(512 + h * 64) * S_);
        f4* qd = (f4*)&Qs[0][0];
        f4* kd = (f4*)&Ks[0][0];
        f4* vd = (f4*)&Vs[0][0];
#pragma unroll
        for (int r = 0; r < 8; ++r) {
            int idx = tid + 256 * r;
            qd[idx] = qsrc[idx];
            kd[idx] = ksrc[idx];
            vd[idx] = vsrc[idx];
        }
    }
    __syncthreads();

    const int s = tid >> 1;
    const int half = tid & 1;
    const int tb = half * 64;

    float dots[64];
#pragma unroll
    for (int j = 0; j < 64; ++j) dots[j] = 0.f;

    for (int d = 0; d < 64; ++d) {
        float qd = Qs[d][s];
#pragma unroll
        for (int j4 = 0; j4 < 16; ++j4) {
            f4 kv = *(const f4*)&Ks[d][tb + j4 * 4];
            dots[4 * j4 + 0] += qd * kv.x;
            dots[4 * j4 + 1] += qd * kv.y;
            dots[4 * j4 + 2] += qd * kv.z;
            dots[4 * j4 + 3] += qd * kv.w;
        }
    }

    const float scale = 0.125f;  // 64^-0.5
    float m = -INFINITY;
#pragma unroll
    for (int j = 0; j < 64; ++j) { dots[j] *= scale; m = fmaxf(m, dots[j]); }
    m = fmaxf(m, __shfl_xor(m, 1));
    float sum = 0.f;
#pragma unroll
    for (int j = 0; j < 64; ++j) { float e = __expf(dots[j] - m); dots[j] = e; sum += e; }
    sum += __shfl_xor(sum, 1);
    float inv = 1.f / sum;
#pragma unroll
    for (int j = 0; j < 64; ++j) dots[j] *= inv;

    // column sums (over s)
    {
        const int wave = tid >> 6;
        const int lane = tid & 63;
#pragma unroll
        for (int j = 0; j < 64; ++j) {
            float c = dots[j];
            c += __shfl_xor(c, 2);
            c += __shfl_xor(c, 4);
            c += __shfl_xor(c, 8);
            c += __shfl_xor(c, 16);
            c += __shfl_xor(c, 32);
            if (lane == half) part[wave][tb + j] = c;
        }
    }
    __syncthreads();
    if (tid < 128) colsum[tid] = part[0][tid] + part[1][tid] + part[2][tid] + part[3][tid];
    __syncthreads();
    if (tid < 64) {
        float v0 = colsum[tid], v1 = colsum[tid + 64];
        float bv; int bi;
        if (v1 > v0) { bv = v1; bi = tid + 64; } else { bv = v0; bi = tid; }
#pragma unroll
        for (int msk = 1; msk <= 32; msk <<= 1) {
            float ov = __shfl_xor(bv, msk);
            int oi = __shfl_xor(bi, msk);
            if (ov > bv || (ov == bv && oi < bi)) { bv = ov; bi = oi; }
        }
        if (tid == 0) idx_out[((n0 + n_l) * H_ + h) * P_ + p] = bi;
    }

    // O = attn * V^T
    for (int d0 = 0; d0 < 64; d0 += 8) {
        float po[8];
#pragma unroll
        for (int i = 0; i < 8; ++i) {
            float acc = 0.f;
#pragma unroll
            for (int j4 = 0; j4 < 16; ++j4) {
                f4 vv = *(const f4*)&Vs[d0 + i][tb + 4 * j4];
                acc += dots[4 * j4 + 0] * vv.x + dots[4 * j4 + 1] * vv.y +
                       dots[4 * j4 + 2] * vv.z + dots[4 * j4 + 3] * vv.w;
            }
            po[i] = acc;
        }
#pragma unroll
        for (int i = 0; i < 8; ++i) po[i] += __shfl_xor(po[i], 1);
        if (half == 0) {
#pragma unroll
            for (int i = 0; i < 8; ++i)
                o_out[((size_t)np_l * 768 + h * 64 + d0 + i) * S_ + s] = po[i];
        }
    }
}

// ---------------------------------------------------------------------------
__global__ void bn_stats(const float* __restrict__ wpvT,
                         const float* __restrict__ gamma,
                         const float* __restrict__ beta,
                         float* __restrict__ aArr, float* __restrict__ bArr)
{
    int i = blockIdx.x * blockDim.x + threadIdx.x;  // p*C + c
    if (i >= P_ * C_) return;
    int p = i / C_, c = i % C_;
    const float* basep = wpvT + (size_t)p * N_ * C_ + c;
    float su = 0.f, s2 = 0.f;
    for (int n = 0; n < N_; ++n) {
        float v = basep[n * C_];
        su += v; s2 += v * v;
    }
    float mean = su * (1.f / N_);
    float var = s2 * (1.f / N_) - mean * mean;
    float rstd = rsqrtf(var + 1e-5f);
    float a = gamma[i] * rstd;
    aArr[i] = a;
    bArr[i] = beta[i] - mean * a;
}

__global__ __launch_bounds__(256) void cls_kernel(
    const float* __restrict__ wpvT,
    const float* __restrict__ aArr, const float* __restrict__ bArr,
    const float* __restrict__ fc, float* __restrict__ cls)
{
    __shared__ float pf[C_];
    const int np = blockIdx.x;
    const int n = np >> 4, p = np & 15;
    const int tid = threadIdx.x;
    {
        float w = wpvT[((size_t)p * N_ + n) * C_ + tid];
        pf[tid] = w * aArr[p * C_ + tid] + bArr[p * C_ + tid];
    }
    __syncthreads();
    for (int k = tid; k < CLS_; k += 256) {
        float acc = 0.f;
#pragma unroll 8
        for (int c = 0; c < C_; ++c) acc += pf[c] * fc[(size_t)c * CLS_ + k];
        cls[(size_t)np * CLS_ + k] = acc;
    }
}

__global__ void sel_kernel(const float* __restrict__ t_f,
                           const int* __restrict__ idxArr,
                           float* __restrict__ selT)
{
    const int np = blockIdx.x;
    const int n = np >> 4, p = np & 15;
    const int c = threadIdx.x;
    float acc = 0.f;
#pragma unroll
    for (int h = 0; h < H_; ++h) {
        int s = idxArr[(n * H_ + h) * P_ + p];
        acc += t_f[((size_t)np * C_ + c) * S_ + s];
    }
    selT[((size_t)p * N_ + n) * C_ + c] = acc;
}

// ---------------------------------------------------------------------------
extern "C" void kernel_launch(void* const* d_in, const int* in_sizes, int n_in,
                              void* d_out, int out_size, void* d_ws, size_t ws_size,
                              hipStream_t stream)
{
    const float* t_f     = (const float*)d_in[0];
    const float* t_s     = (const float*)d_in[1];
    const float* t_l     = (const float*)d_in[2];
    const float* decay_w = (const float*)d_in[3];
    const float* qkv_w   = (const float*)d_in[4];
    const float* out_w   = (const float*)d_in[5];
    const float* gamma   = (const float*)d_in[6];
    const float* beta    = (const float*)d_in[7];
    const float* fc      = (const float*)d_in[8];
    float* out = (float*)d_out;

    // --- workspace layout: small arrays at head, big chunk buffers after ---
    float* ws   = (float*)d_ws;
    float* aArr = ws;                          // P*C
    float* bArr = aArr + P_ * C_;              // P*C
    int*   idxA = (int*)(bArr + P_ * C_);      // N*H*P ints
    float* big  = (float*)(idxA + N_ * H_ * P_);   // 16B-aligned (10240 floats in)

    const size_t head = (size_t)(big - ws);
    const size_t total_f = ws_size / sizeof(float);
    const size_t avail = (total_f > head) ? (total_f - head) : 0;
    const size_t per_n = (size_t)P_ * 4 * C_ * S_;   // t_all(C) + qkv(3C) rows per n
    int chunk = (int)(avail / per_n);
    if (chunk < 1) chunk = 1;
    if (chunk > N_) chunk = N_;
    const int nch = (N_ + chunk - 1) / chunk;
    chunk = (N_ + nch - 1) / nch;              // balance chunk sizes

    float* t_all = big;                                        // chunk*P*C*S
    float* qkv   = big + (size_t)chunk * P_ * C_ * S_;         // chunk*P*3C*S

    float* cls  = out;
    float* wpvT = out + (size_t)N_ * P_ * CLS_;
    float* selT = wpvT + (size_t)P_ * N_ * C_;

    dim3 blk(256);
    for (int n0 = 0; n0 < N_; n0 += chunk) {
        const int cn = (N_ - n0 < chunk) ? (N_ - n0) : chunk;
        gemm_np<0, 768><<<dim3(4, cn * P_), blk, 0, stream>>>(
            decay_w, t_f, t_s, t_l, nullptr, t_all, n0);
        gemm_np<1, 256><<<dim3(12, cn * P_), blk, 0, stream>>>(
            qkv_w, t_all, nullptr, nullptr, nullptr, qkv, n0);
        attn_kernel<<<cn * H_ * P_, blk, 0, stream>>>(qkv, qkv, idxA, n0);
        gemm_np<2, 256><<<dim3(4, cn * P_), blk, 0, stream>>>(
            out_w, qkv, nullptr, nullptr, t_all, wpvT, n0);
    }
    bn_stats<<<(P_ * C_ + 255) / 256, 256, 0, stream>>>(wpvT, gamma, beta, aArr, bArr);
    sel_kernel<<<N_ * P_, blk, 0, stream>>>(t_f, idxA, selT);
    cls_kernel<<<N_ * P_, blk, 0, stream>>>(wpvT, aArr, bArr, fc, cls);
}

// Round 3
// 863.071 us; speedup vs baseline: 1.7588x; 1.7588x over previous
//
#include <hip/hip_runtime.h>
#include <math.h>

#define N_ 32
#define P_ 16
#define C_ 256
#define S_ 128
#define H_ 4
#define CLS_ 3000

typedef __attribute__((ext_vector_type(4))) float f4v;
typedef __attribute__((ext_vector_type(4))) float f32x4;
typedef __attribute__((ext_vector_type(8))) short short8;
typedef __attribute__((ext_vector_type(4))) unsigned short us4;

__device__ __forceinline__ unsigned short f2bf(float x){
    unsigned u = __float_as_uint(x);
    u += 0x7fffu + ((u >> 16) & 1u);
    return (unsigned short)(u >> 16);
}
__device__ __forceinline__ float bf2f(unsigned short h){
    return __uint_as_float(((unsigned)h) << 16);
}

// ---------------------------------------------------------------------------
// Split weights fp32 -> bf16 hi/lo (decay_w, qkv_w) and hi-only (out_w)
// ---------------------------------------------------------------------------
__global__ void wsplit(const float* __restrict__ dw, const float* __restrict__ qw,
                       const float* __restrict__ ow,
                       unsigned short* __restrict__ wdh, unsigned short* __restrict__ wdl,
                       unsigned short* __restrict__ wqh, unsigned short* __restrict__ wql,
                       unsigned short* __restrict__ woh){
    int i = blockIdx.x * 256 + threadIdx.x;
    int stride = gridDim.x * 256;
    for (; i < 3145728; i += stride){
        float a = dw[i]; unsigned short h = f2bf(a);
        wdh[i] = h; wdl[i] = f2bf(a - bf2f(h));
        float b = qw[i]; unsigned short h2 = f2bf(b);
        wqh[i] = h2; wql[i] = f2bf(b - bf2f(h2));
        if (i < 1048576) woh[i] = f2bf(ow[i]);
    }
}

// ---------------------------------------------------------------------------
// Transpose inputs: xcatT[np_l][s][t*256+c] = t_x[np_g][c][s]   (fp32)
// lane = c (L1 line reuse over s); writes coalesced.
// ---------------------------------------------------------------------------
__global__ __launch_bounds__(256) void xT_kernel(
    const float* __restrict__ t_f, const float* __restrict__ t_s,
    const float* __restrict__ t_l, float* __restrict__ xcatT, int n0){
    const int np_l = blockIdx.x, tsel = blockIdx.y;
    const float* src = (tsel == 0) ? t_f : ((tsel == 1) ? t_s : t_l);
    const size_t np_g = (size_t)(n0 * 16) + np_l;
    const float* sp = src + (np_g * 256 + threadIdx.x) * 128;
    float* dp = xcatT + (size_t)np_l * 128 * 768 + tsel * 256 + threadIdx.x;
#pragma unroll 4
    for (int s = 0; s < 128; ++s) dp[(size_t)s * 768] = sp[s];
}

// ---------------------------------------------------------------------------
// Split-bf16 MFMA GEMM:  D[s][o] = sum_k A[s][k] * W[o][k]
// A: fp32 activations [np_l*128+s][APITCH] (col offset 0), split to hi/lo at staging.
// W: pre-split bf16 [P][ND][KEXT].
// MODE 0/1: store fp32 D to outp[np_l*128+s][OPITCH]+o
// MODE 2 (1-term): epilogue  wpvT[p][n][c] = max_s(D + resid)
// block 256 = 4 waves; tile 128s x 128o; wave 64x64; BK=64.
// ---------------------------------------------------------------------------
template<int KEXT, int APITCH, int ND, int MODE, int OPITCH>
__global__ __launch_bounds__(256) void gemm3(
    const float* __restrict__ Aact, const unsigned short* __restrict__ Whi,
    const unsigned short* __restrict__ Wlo, const float* __restrict__ resid,
    float* __restrict__ outp, int n0)
{
    constexpr int T3 = (MODE == 2) ? 0 : 1;
    __shared__ unsigned short sm[(T3 ? 4 : 2) * 128 * 72];
    unsigned short* Ah = sm;
    unsigned short* Bh = sm + 128 * 72;
    unsigned short* Al = T3 ? (sm + 2 * 128 * 72) : sm;
    unsigned short* Bl = T3 ? (sm + 3 * 128 * 72) : sm;
    __shared__ float cmax[2][2][64];

    const int tid = threadIdx.x;
    const int w = tid >> 6, l = tid & 63;
    const int lr = l & 15, lg = l >> 4;
    const int ws0 = (w & 1) * 64, wo0 = (w >> 1) * 64;
    const int o0 = blockIdx.x * 128;
    const int np_l = blockIdx.y;
    const int p = np_l & 15;
    const size_t aBase = (size_t)np_l * 128 * APITCH;
    const unsigned short* Wp_h = Whi + ((size_t)p * ND + o0) * KEXT;
    const unsigned short* Wp_l = T3 ? (Wlo + ((size_t)p * ND + o0) * KEXT) : Wp_h;

    f32x4 acc[4][4];
#pragma unroll
    for (int i = 0; i < 4; ++i)
#pragma unroll
        for (int j = 0; j < 4; ++j) acc[i][j] = (f32x4){0.f, 0.f, 0.f, 0.f};

    for (int k0 = 0; k0 < KEXT; k0 += 64){
        // --- A stage: fp32 -> hi/lo bf16, [128][72] padded ---
#pragma unroll
        for (int it = 0; it < 8; ++it){
            int idx = tid + 256 * it;
            int s = idx >> 4, k4 = (idx & 15) * 4;
            f4v v = *(const f4v*)(Aact + aBase + (size_t)s * APITCH + k0 + k4);
            unsigned short h0 = f2bf(v[0]), h1 = f2bf(v[1]), h2 = f2bf(v[2]), h3 = f2bf(v[3]);
            *(us4*)(Ah + s * 72 + k4) = (us4){h0, h1, h2, h3};
            if (T3){
                us4 lo = { f2bf(v[0] - bf2f(h0)), f2bf(v[1] - bf2f(h1)),
                           f2bf(v[2] - bf2f(h2)), f2bf(v[3] - bf2f(h3)) };
                *(us4*)(Al + s * 72 + k4) = lo;
            }
        }
        // --- B stage: bf16 copy ---
#pragma unroll
        for (int it = 0; it < 4; ++it){
            int idx = tid + 256 * it;
            int o = idx >> 3, k8 = (idx & 7) * 8;
            *(short8*)(Bh + o * 72 + k8) = *(const short8*)(Wp_h + (size_t)o * KEXT + k0 + k8);
            if (T3)
                *(short8*)(Bl + o * 72 + k8) = *(const short8*)(Wp_l + (size_t)o * KEXT + k0 + k8);
        }
        __syncthreads();
#pragma unroll
        for (int ks = 0; ks < 2; ++ks){
            short8 ah[4], al[4];
#pragma unroll
            for (int sf = 0; sf < 4; ++sf){
                int row = ws0 + sf * 16 + lr;
                ah[sf] = *(const short8*)(Ah + row * 72 + ks * 32 + lg * 8);
                if (T3) al[sf] = *(const short8*)(Al + row * 72 + ks * 32 + lg * 8);
            }
#pragma unroll
            for (int of = 0; of < 4; ++of){
                int row = wo0 + of * 16 + lr;
                short8 bh = *(const short8*)(Bh + row * 72 + ks * 32 + lg * 8);
                short8 bl = bh;
                if (T3) bl = *(const short8*)(Bl + row * 72 + ks * 32 + lg * 8);
#pragma unroll
                for (int sf = 0; sf < 4; ++sf){
                    acc[sf][of] = __builtin_amdgcn_mfma_f32_16x16x32_bf16(ah[sf], bh, acc[sf][of], 0, 0, 0);
                    if (T3){
                        acc[sf][of] = __builtin_amdgcn_mfma_f32_16x16x32_bf16(ah[sf], bl, acc[sf][of], 0, 0, 0);
                        acc[sf][of] = __builtin_amdgcn_mfma_f32_16x16x32_bf16(al[sf], bh, acc[sf][of], 0, 0, 0);
                    }
                }
            }
        }
        __syncthreads();
    }

    if (MODE != 2){
#pragma unroll
        for (int sf = 0; sf < 4; ++sf)
#pragma unroll
            for (int of = 0; of < 4; ++of){
                int oc = o0 + wo0 + of * 16 + lr;
#pragma unroll
                for (int r = 0; r < 4; ++r){
                    int s = ws0 + sf * 16 + lg * 4 + r;
                    outp[(size_t)np_l * 128 * OPITCH + (size_t)s * OPITCH + oc] = acc[sf][of][r];
                }
            }
    } else {
        const int n_g = n0 + (np_l >> 4);
#pragma unroll
        for (int of = 0; of < 4; ++of){
            int oc = o0 + wo0 + of * 16 + lr;
            float m = -INFINITY;
#pragma unroll
            for (int sf = 0; sf < 4; ++sf){
#pragma unroll
                for (int r = 0; r < 4; ++r){
                    int s = ws0 + sf * 16 + lg * 4 + r;
                    float v = acc[sf][of][r] + resid[(size_t)np_l * 128 * 256 + (size_t)s * 256 + oc];
                    m = fmaxf(m, v);
                }
            }
            m = fmaxf(m, __shfl_xor(m, 16));
            m = fmaxf(m, __shfl_xor(m, 32));
            if (l < 16) cmax[w >> 1][w & 1][of * 16 + l] = m;
        }
        __syncthreads();
        if (tid < 128){
            int oh = tid >> 6, col = tid & 63;
            float v = fmaxf(cmax[oh][0][col], cmax[oh][1][col]);
            outp[((size_t)p * N_ + n_g) * C_ + o0 + oh * 64 + col] = v;
        }
    }
}

// ---------------------------------------------------------------------------
// Attention per (n,h,p): 3-term split QK^T MFMA, fp32 softmax+colsum (argmax),
// bf16 PV MFMA; O (fp32) overwrites q-cols of qkv.
// ---------------------------------------------------------------------------
__global__ __launch_bounds__(256) void attn3(float* __restrict__ qkv,
                                             int* __restrict__ idxA, int n0){
    __shared__ char smraw[17408 + 34816 + 2048];
    unsigned short* Vs = (unsigned short*)smraw;             // [64][136] bf16
    unsigned short* Pm = (unsigned short*)(smraw + 17408);   // [128][136] bf16
    float* csW = (float*)(smraw + 17408 + 34816);            // [4][128]
    float* Ot  = (float*)smraw;                              // [128][72] f32 (alias)

    const int b = blockIdx.x;
    const int n_l = b >> 6, h = (b >> 4) & 3, p = b & 15;
    const int np_l = n_l * 16 + p;
    const int tid = threadIdx.x, w = tid >> 6, l = tid & 63;
    const int lr = l & 15, lg = l >> 4;
    float* base = qkv + (size_t)np_l * 128 * 768;

    // stage V: fp32 [t][d] -> bf16 Vs[d][t]
#pragma unroll
    for (int it = 0; it < 8; ++it){
        int idx = tid + 256 * it;
        int t = idx >> 4, d4 = (idx & 15) * 4;
        f4v v = *(const f4v*)(base + (size_t)t * 768 + 512 + h * 64 + d4);
#pragma unroll
        for (int j = 0; j < 4; ++j) Vs[(d4 + j) * 136 + t] = f2bf(v[j]);
    }

    // Q fragments (hi/lo)
    short8 qh[2][2], ql[2][2];
#pragma unroll
    for (int sf = 0; sf < 2; ++sf)
#pragma unroll
        for (int ks = 0; ks < 2; ++ks){
            const float* qp = base + (size_t)(w * 32 + sf * 16 + lr) * 768 + h * 64 + ks * 32 + lg * 8;
            f4v a = *(const f4v*)qp; f4v c = *(const f4v*)(qp + 4);
            short8 hi, lo;
#pragma unroll
            for (int j = 0; j < 4; ++j){
                unsigned short hh = f2bf(a[j]); hi[j] = (short)hh; lo[j] = (short)f2bf(a[j] - bf2f(hh));
                unsigned short h2 = f2bf(c[j]); hi[4 + j] = (short)h2; lo[4 + j] = (short)f2bf(c[j] - bf2f(h2));
            }
            qh[sf][ks] = hi; ql[sf][ks] = lo;
        }

    f32x4 dacc[2][8];
#pragma unroll
    for (int i = 0; i < 2; ++i)
#pragma unroll
        for (int j = 0; j < 8; ++j) dacc[i][j] = (f32x4){0.f, 0.f, 0.f, 0.f};

#pragma unroll
    for (int tf = 0; tf < 8; ++tf){
#pragma unroll
        for (int ks = 0; ks < 2; ++ks){
            const float* kp = base + (size_t)(tf * 16 + lr) * 768 + 256 + h * 64 + ks * 32 + lg * 8;
            f4v a = *(const f4v*)kp; f4v c = *(const f4v*)(kp + 4);
            short8 kh, kl;
#pragma unroll
            for (int j = 0; j < 4; ++j){
                unsigned short hh = f2bf(a[j]); kh[j] = (short)hh; kl[j] = (short)f2bf(a[j] - bf2f(hh));
                unsigned short h2 = f2bf(c[j]); kh[4 + j] = (short)h2; kl[4 + j] = (short)f2bf(c[j] - bf2f(h2));
            }
#pragma unroll
            for (int sf = 0; sf < 2; ++sf){
                dacc[sf][tf] = __builtin_amdgcn_mfma_f32_16x16x32_bf16(qh[sf][ks], kh, dacc[sf][tf], 0, 0, 0);
                dacc[sf][tf] = __builtin_amdgcn_mfma_f32_16x16x32_bf16(qh[sf][ks], kl, dacc[sf][tf], 0, 0, 0);
                dacc[sf][tf] = __builtin_amdgcn_mfma_f32_16x16x32_bf16(ql[sf][ks], kh, dacc[sf][tf], 0, 0, 0);
            }
        }
    }

    // softmax (rows of this wave) + write P bf16 + fp32 colsum partials
    float csp[8];
#pragma unroll
    for (int tf = 0; tf < 8; ++tf) csp[tf] = 0.f;
#pragma unroll
    for (int sf = 0; sf < 2; ++sf){
#pragma unroll
        for (int r = 0; r < 4; ++r){
            float m = -INFINITY;
#pragma unroll
            for (int tf = 0; tf < 8; ++tf) m = fmaxf(m, dacc[sf][tf][r]);
            m = fmaxf(m, __shfl_xor(m, 1)); m = fmaxf(m, __shfl_xor(m, 2));
            m = fmaxf(m, __shfl_xor(m, 4)); m = fmaxf(m, __shfl_xor(m, 8));
            float e[8]; float sum = 0.f;
#pragma unroll
            for (int tf = 0; tf < 8; ++tf){
                e[tf] = __expf(0.125f * (dacc[sf][tf][r] - m)); sum += e[tf];
            }
            sum += __shfl_xor(sum, 1); sum += __shfl_xor(sum, 2);
            sum += __shfl_xor(sum, 4); sum += __shfl_xor(sum, 8);
            float inv = 1.f / sum;
            int s = w * 32 + sf * 16 + lg * 4 + r;
#pragma unroll
            for (int tf = 0; tf < 8; ++tf){
                float pv = e[tf] * inv;
                Pm[s * 136 + tf * 16 + lr] = f2bf(pv);
                csp[tf] += pv;
            }
        }
    }
#pragma unroll
    for (int tf = 0; tf < 8; ++tf){
        float v = csp[tf];
        v += __shfl_xor(v, 16); v += __shfl_xor(v, 32);
        if (l < 16) csW[w * 128 + tf * 16 + l] = v;
    }
    __syncthreads();

    // PV: D[d][s] = sum_t V[d][t] P[s][t]
    f32x4 oacc[8];
#pragma unroll
    for (int i = 0; i < 8; ++i) oacc[i] = (f32x4){0.f, 0.f, 0.f, 0.f};
#pragma unroll
    for (int ks = 0; ks < 4; ++ks){
        short8 av = *(const short8*)(Vs + (w * 16 + lr) * 136 + ks * 32 + lg * 8);
#pragma unroll
        for (int sf = 0; sf < 8; ++sf){
            short8 bp = *(const short8*)(Pm + (sf * 16 + lr) * 136 + ks * 32 + lg * 8);
            oacc[sf] = __builtin_amdgcn_mfma_f32_16x16x32_bf16(av, bp, oacc[sf], 0, 0, 0);
        }
    }
    __syncthreads();

    // argmax of colsum (fp32) — first occurrence
    if (tid < 64){
        float v0 = csW[tid] + csW[128 + tid] + csW[256 + tid] + csW[384 + tid];
        float v1 = csW[64 + tid] + csW[192 + tid] + csW[320 + tid] + csW[448 + tid];
        float bv; int bi;
        if (v1 > v0){ bv = v1; bi = 64 + tid; } else { bv = v0; bi = tid; }
#pragma unroll
        for (int msk = 1; msk <= 32; msk <<= 1){
            float ov = __shfl_xor(bv, msk); int oi = __shfl_xor(bi, msk);
            if (ov > bv || (ov == bv && oi < bi)){ bv = ov; bi = oi; }
        }
        if (tid == 0){ int n_g = n0 + n_l; idxA[(n_g * H_ + h) * P_ + p] = bi; }
    }

    // O frags -> Ot[s][d] (f32), then coalesced store over q-cols
#pragma unroll
    for (int sf = 0; sf < 8; ++sf){
        int s = sf * 16 + lr;
#pragma unroll
        for (int r = 0; r < 4; ++r) Ot[s * 72 + w * 16 + lg * 4 + r] = oacc[sf][r];
    }
    __syncthreads();
#pragma unroll
    for (int it = 0; it < 8; ++it){
        int idx = tid + 256 * it;
        int s = idx >> 4, d4 = (idx & 15) * 4;
        *(f4v*)(base + (size_t)s * 768 + h * 64 + d4) = *(const f4v*)(Ot + s * 72 + d4);
    }
}

// ---------------------------------------------------------------------------
__global__ void bn_stats(const float* __restrict__ wpvT,
                         const float* __restrict__ gamma,
                         const float* __restrict__ beta,
                         float* __restrict__ aArr, float* __restrict__ bArr)
{
    int i = blockIdx.x * blockDim.x + threadIdx.x;
    if (i >= P_ * C_) return;
    int p = i / C_, c = i % C_;
    const float* basep = wpvT + (size_t)p * N_ * C_ + c;
    float su = 0.f, s2 = 0.f;
    for (int n = 0; n < N_; ++n){
        float v = basep[n * C_];
        su += v; s2 += v * v;
    }
    float mean = su * (1.f / N_);
    float var = s2 * (1.f / N_) - mean * mean;
    float rstd = rsqrtf(var + 1e-5f);
    float a = gamma[i] * rstd;
    aArr[i] = a;
    bArr[i] = beta[i] - mean * a;
}

__global__ __launch_bounds__(256) void cls_kernel(
    const float* __restrict__ wpvT,
    const float* __restrict__ aArr, const float* __restrict__ bArr,
    const float* __restrict__ fc, float* __restrict__ cls)
{
    __shared__ float pf[C_];
    const int np = blockIdx.x;
    const int n = np >> 4, p = np & 15;
    const int tid = threadIdx.x;
    {
        float wv = wpvT[((size_t)p * N_ + n) * C_ + tid];
        pf[tid] = wv * aArr[p * C_ + tid] + bArr[p * C_ + tid];
    }
    __syncthreads();
    for (int k = tid; k < CLS_; k += 256){
        float acc = 0.f;
#pragma unroll 8
        for (int c = 0; c < C_; ++c) acc += pf[c] * fc[(size_t)c * CLS_ + k];
        cls[(size_t)np * CLS_ + k] = acc;
    }
}

__global__ void sel_kernel(const float* __restrict__ t_f,
                           const int* __restrict__ idxArr,
                           float* __restrict__ selT)
{
    const int np = blockIdx.x;
    const int n = np >> 4, p = np & 15;
    const int c = threadIdx.x;
    float acc = 0.f;
#pragma unroll
    for (int h = 0; h < H_; ++h){
        int s = idxArr[(n * H_ + h) * P_ + p];
        acc += t_f[((size_t)np * C_ + c) * S_ + s];
    }
    selT[((size_t)p * N_ + n) * C_ + c] = acc;
}

// ---------------------------------------------------------------------------
extern "C" void kernel_launch(void* const* d_in, const int* in_sizes, int n_in,
                              void* d_out, int out_size, void* d_ws, size_t ws_size,
                              hipStream_t stream)
{
    const float* t_f     = (const float*)d_in[0];
    const float* t_s     = (const float*)d_in[1];
    const float* t_l     = (const float*)d_in[2];
    const float* decay_w = (const float*)d_in[3];
    const float* qkv_w   = (const float*)d_in[4];
    const float* out_w   = (const float*)d_in[5];
    const float* gamma   = (const float*)d_in[6];
    const float* beta    = (const float*)d_in[7];
    const float* fc      = (const float*)d_in[8];
    float* out = (float*)d_out;

    // ---- ws layout: split weights at head, then chunked activations ----
    const size_t WD = 3145728, WQ = 3145728, WO = 1048576;
    char* basep = (char*)d_ws;
    unsigned short* wdh = (unsigned short*)basep;
    unsigned short* wdl = wdh + WD;
    unsigned short* wqh = wdl + WD;
    unsigned short* wql = wqh + WQ;
    unsigned short* woh = wql + WQ;
    float* aArr = (float*)(woh + WO);
    float* bArr = aArr + P_ * C_;
    int* idxA = (int*)(bArr + P_ * C_);
    char* big = (char*)(idxA + N_ * H_ * P_);
    size_t head = (size_t)(big - basep);
    size_t avail = (ws_size > head) ? (ws_size - head) : 0;
    const size_t per_n = (size_t)16 * 128 * (768 + 256 + 768) * 4;  // 14.68 MB
    int cn = (int)(avail / per_n);
    if (cn < 1) cn = 1;
    if (cn > N_) cn = N_;
    int nch = (N_ + cn - 1) / cn;
    cn = (N_ + nch - 1) / nch;

    float* xcatT = (float*)big;                               // cn*16*128*768
    float* tallT = xcatT + (size_t)cn * 16 * 128 * 768;       // cn*16*128*256
    float* qkvB  = tallT + (size_t)cn * 16 * 128 * 256;       // cn*16*128*768

    float* cls  = out;
    float* wpvT = out + (size_t)N_ * P_ * CLS_;
    float* selT = wpvT + (size_t)P_ * N_ * C_;

    wsplit<<<4096, 256, 0, stream>>>(decay_w, qkv_w, out_w, wdh, wdl, wqh, wql, woh);

    for (int n0 = 0; n0 < N_; n0 += cn){
        int c = (N_ - n0 < cn) ? (N_ - n0) : cn;
        int npg = c * 16;
        xT_kernel<<<dim3(npg, 3), 256, 0, stream>>>(t_f, t_s, t_l, xcatT, n0);
        gemm3<768, 768, 256, 0, 256><<<dim3(2, npg), 256, 0, stream>>>(
            xcatT, wdh, wdl, nullptr, tallT, n0);
        gemm3<256, 256, 768, 1, 768><<<dim3(6, npg), 256, 0, stream>>>(
            tallT, wqh, wql, nullptr, qkvB, n0);
        attn3<<<dim3(c * 64), 256, 0, stream>>>(qkvB, idxA, n0);
        gemm3<256, 768, 256, 2, 256><<<dim3(2, npg), 256, 0, stream>>>(
            qkvB, woh, nullptr, tallT, wpvT, n0);
    }
    bn_stats<<<(P_ * C_ + 255) / 256, 256, 0, stream>>>(wpvT, gamma, beta, aArr, bArr);
    sel_kernel<<<N_ * P_, 256, 0, stream>>>(t_f, idxA, selT);
    cls_kernel<<<N_ * P_, 256, 0, stream>>>(wpvT, aArr, bArr, fc, cls);
}

// Round 4
// 574.298 us; speedup vs baseline: 2.6431x; 1.5028x over previous
//
#include <hip/hip_runtime.h>
#include <math.h>

#define N_ 32
#define P_ 16
#define C_ 256
#define S_ 128
#define H_ 4
#define CLS_ 3000

typedef __attribute__((ext_vector_type(4))) float f4v;
typedef __attribute__((ext_vector_type(4))) float f32x4;
typedef __attribute__((ext_vector_type(8))) short short8;
typedef __attribute__((ext_vector_type(4))) unsigned short us4;

__device__ __forceinline__ unsigned short f2bf(float x){
    unsigned u = __float_as_uint(x);
    u += 0x7fffu + ((u >> 16) & 1u);
    return (unsigned short)(u >> 16);
}
__device__ __forceinline__ float bf2f(unsigned short h){
    return __uint_as_float(((unsigned)h) << 16);
}

// ---------------------------------------------------------------------------
// Split weights fp32 -> bf16 hi/lo (decay_w, qkv_w) and hi-only (out_w)
// ---------------------------------------------------------------------------
__global__ void wsplit(const float* __restrict__ dw, const float* __restrict__ qw,
                       const float* __restrict__ ow,
                       unsigned short* __restrict__ wdh, unsigned short* __restrict__ wdl,
                       unsigned short* __restrict__ wqh, unsigned short* __restrict__ wql,
                       unsigned short* __restrict__ woh){
    int i = blockIdx.x * 256 + threadIdx.x;
    int stride = gridDim.x * 256;
    for (; i < 3145728; i += stride){
        float a = dw[i]; unsigned short h = f2bf(a);
        wdh[i] = h; wdl[i] = f2bf(a - bf2f(h));
        float b = qw[i]; unsigned short h2 = f2bf(b);
        wqh[i] = h2; wql[i] = f2bf(b - bf2f(h2));
        if (i < 1048576) woh[i] = f2bf(ow[i]);
    }
}

// fc [256][3000] fp32 -> fcT [3072][256] bf16 (rows >= 3000 zeroed)
__global__ __launch_bounds__(256) void fct_kernel(const float* __restrict__ fc,
                                                  unsigned short* __restrict__ fcT){
    int n = blockIdx.x * 256 + threadIdx.x;   // 0..3071
    if (n < CLS_){
        for (int c = 0; c < 256; ++c) fcT[(size_t)n * 256 + c] = f2bf(fc[(size_t)c * CLS_ + n]);
    } else {
        for (int c = 0; c < 256; ++c) fcT[(size_t)n * 256 + c] = 0;
    }
}

// ---------------------------------------------------------------------------
// Transpose inputs -> bf16 hi/lo planes: x{H,L}[np_l][s][t*256+c]
// ---------------------------------------------------------------------------
__global__ __launch_bounds__(256) void xT_kernel(
    const float* __restrict__ t_f, const float* __restrict__ t_s,
    const float* __restrict__ t_l,
    unsigned short* __restrict__ xH, unsigned short* __restrict__ xL, int n0){
    const int np_l = blockIdx.x, tsel = blockIdx.y;
    const float* src = (tsel == 0) ? t_f : ((tsel == 1) ? t_s : t_l);
    const size_t np_g = (size_t)(n0 * 16) + np_l;
    const float* sp = src + (np_g * 256 + threadIdx.x) * 128;
    size_t doff = (size_t)np_l * 128 * 768 + tsel * 256 + threadIdx.x;
#pragma unroll 4
    for (int s = 0; s < 128; ++s){
        float v = sp[s];
        unsigned short hh = f2bf(v);
        xH[doff + (size_t)s * 768] = hh;
        xL[doff + (size_t)s * 768] = f2bf(v - bf2f(hh));
    }
}

// ---------------------------------------------------------------------------
// Split-bf16 MFMA GEMM:  D[s][o] = sum_k A[s][k] * W[o][k]
// A: bf16 hi/lo planes [np_l*128+s][APITCH]; W: pre-split bf16 [P][ND][KEXT].
// MODE 0/1 (3-term): write hi/lo bf16 planes outH/outL pitch OPITCH
// MODE 2 (1-term): epilogue wpvT[p][n][c] = max_s(D + residH+residL)
// block 256 = 4 waves; tile 128s x 128o; wave 64x64; BK=64.
// ---------------------------------------------------------------------------
template<int KEXT, int APITCH, int ND, int MODE, int OPITCH>
__global__ __launch_bounds__(256) void gemm3(
    const unsigned short* __restrict__ Ah_g, const unsigned short* __restrict__ Al_g,
    const unsigned short* __restrict__ Whi, const unsigned short* __restrict__ Wlo,
    const unsigned short* __restrict__ resH, const unsigned short* __restrict__ resL,
    unsigned short* __restrict__ outH, unsigned short* __restrict__ outL,
    float* __restrict__ outF, int n0)
{
    constexpr int T3 = (MODE == 2) ? 0 : 1;
    __shared__ unsigned short sm[(T3 ? 4 : 2) * 128 * 72];
    unsigned short* AhL = sm;
    unsigned short* BhL = sm + 128 * 72;
    unsigned short* AlL = T3 ? (sm + 2 * 128 * 72) : sm;
    unsigned short* BlL = T3 ? (sm + 3 * 128 * 72) : sm;
    __shared__ float cmax[2][2][64];

    const int tid = threadIdx.x;
    const int w = tid >> 6, l = tid & 63;
    const int lr = l & 15, lg = l >> 4;
    const int ws0 = (w & 1) * 64, wo0 = (w >> 1) * 64;
    const int o0 = blockIdx.x * 128;
    const int np_l = blockIdx.y;
    const int p = np_l & 15;
    const size_t aBase = (size_t)np_l * 128 * APITCH;
    const unsigned short* Wp_h = Whi + ((size_t)p * ND + o0) * KEXT;
    const unsigned short* Wp_l = T3 ? (Wlo + ((size_t)p * ND + o0) * KEXT) : Wp_h;

    f32x4 acc[4][4];
#pragma unroll
    for (int i = 0; i < 4; ++i)
#pragma unroll
        for (int j = 0; j < 4; ++j) acc[i][j] = (f32x4){0.f, 0.f, 0.f, 0.f};

    for (int k0 = 0; k0 < KEXT; k0 += 64){
        // --- A stage: bf16 copy (hi, and lo if 3-term) ---
#pragma unroll
        for (int it = 0; it < 4; ++it){
            int idx = tid + 256 * it;
            int s = idx >> 3, c8 = (idx & 7) * 8;
            *(short8*)(AhL + s * 72 + c8) =
                *(const short8*)(Ah_g + aBase + (size_t)s * APITCH + k0 + c8);
            if (T3)
                *(short8*)(AlL + s * 72 + c8) =
                    *(const short8*)(Al_g + aBase + (size_t)s * APITCH + k0 + c8);
        }
        // --- B stage: bf16 copy ---
#pragma unroll
        for (int it = 0; it < 4; ++it){
            int idx = tid + 256 * it;
            int o = idx >> 3, k8 = (idx & 7) * 8;
            *(short8*)(BhL + o * 72 + k8) = *(const short8*)(Wp_h + (size_t)o * KEXT + k0 + k8);
            if (T3)
                *(short8*)(BlL + o * 72 + k8) = *(const short8*)(Wp_l + (size_t)o * KEXT + k0 + k8);
        }
        __syncthreads();
#pragma unroll
        for (int ks = 0; ks < 2; ++ks){
            short8 ah[4], al[4];
#pragma unroll
            for (int sf = 0; sf < 4; ++sf){
                int row = ws0 + sf * 16 + lr;
                ah[sf] = *(const short8*)(AhL + row * 72 + ks * 32 + lg * 8);
                if (T3) al[sf] = *(const short8*)(AlL + row * 72 + ks * 32 + lg * 8);
            }
#pragma unroll
            for (int of = 0; of < 4; ++of){
                int row = wo0 + of * 16 + lr;
                short8 bh = *(const short8*)(BhL + row * 72 + ks * 32 + lg * 8);
                short8 bl = bh;
                if (T3) bl = *(const short8*)(BlL + row * 72 + ks * 32 + lg * 8);
#pragma unroll
                for (int sf = 0; sf < 4; ++sf){
                    acc[sf][of] = __builtin_amdgcn_mfma_f32_16x16x32_bf16(ah[sf], bh, acc[sf][of], 0, 0, 0);
                    if (T3){
                        acc[sf][of] = __builtin_amdgcn_mfma_f32_16x16x32_bf16(ah[sf], bl, acc[sf][of], 0, 0, 0);
                        acc[sf][of] = __builtin_amdgcn_mfma_f32_16x16x32_bf16(al[sf], bh, acc[sf][of], 0, 0, 0);
                    }
                }
            }
        }
        __syncthreads();
    }

    if (MODE != 2){
#pragma unroll
        for (int sf = 0; sf < 4; ++sf)
#pragma unroll
            for (int of = 0; of < 4; ++of){
                int oc = o0 + wo0 + of * 16 + lr;
#pragma unroll
                for (int r = 0; r < 4; ++r){
                    int s = ws0 + sf * 16 + lg * 4 + r;
                    size_t di = (size_t)np_l * 128 * OPITCH + (size_t)s * OPITCH + oc;
                    float v = acc[sf][of][r];
                    unsigned short hh = f2bf(v);
                    outH[di] = hh;
                    outL[di] = f2bf(v - bf2f(hh));
                }
            }
    } else {
        const int n_g = n0 + (np_l >> 4);
#pragma unroll
        for (int of = 0; of < 4; ++of){
            int oc = o0 + wo0 + of * 16 + lr;
            float m = -INFINITY;
#pragma unroll
            for (int sf = 0; sf < 4; ++sf){
#pragma unroll
                for (int r = 0; r < 4; ++r){
                    int s = ws0 + sf * 16 + lg * 4 + r;
                    size_t ri = (size_t)np_l * 128 * 256 + (size_t)s * 256 + oc;
                    float v = acc[sf][of][r] + bf2f(resH[ri]) + bf2f(resL[ri]);
                    m = fmaxf(m, v);
                }
            }
            m = fmaxf(m, __shfl_xor(m, 16));
            m = fmaxf(m, __shfl_xor(m, 32));
            if (l < 16) cmax[w >> 1][w & 1][of * 16 + l] = m;
        }
        __syncthreads();
        if (tid < 128){
            int oh = tid >> 6, col = tid & 63;
            float v = fmaxf(cmax[oh][0][col], cmax[oh][1][col]);
            outF[((size_t)p * N_ + n_g) * C_ + o0 + oh * 64 + col] = v;
        }
    }
}

// ---------------------------------------------------------------------------
// Attention per (n,h,p): 3-term split QK^T MFMA (bf16 plane inputs),
// fp32 softmax+colsum (argmax), bf16 PV MFMA; O (bf16 hi) overwrites q-cols.
// ---------------------------------------------------------------------------
__global__ __launch_bounds__(256) void attn3(unsigned short* __restrict__ qH,
                                             const unsigned short* __restrict__ qL,
                                             int* __restrict__ idxA, int n0){
    __shared__ char smraw[17408 + 34816 + 2048];
    unsigned short* Vs = (unsigned short*)smraw;             // [64][136] bf16
    unsigned short* Pm = (unsigned short*)(smraw + 17408);   // [128][136] bf16
    float* csW = (float*)(smraw + 17408 + 34816);            // [4][128]
    unsigned short* Ot = (unsigned short*)smraw;             // [128][72] bf16 (alias)

    const int b = blockIdx.x;
    const int n_l = b >> 6, h = (b >> 4) & 3, p = b & 15;
    const int np_l = n_l * 16 + p;
    const int tid = threadIdx.x, w = tid >> 6, l = tid & 63;
    const int lr = l & 15, lg = l >> 4;
    unsigned short* baseH = qH + (size_t)np_l * 128 * 768;
    const unsigned short* baseL = qL + (size_t)np_l * 128 * 768;

    // stage V: bf16 [t][d] -> Vs[d][t]
#pragma unroll
    for (int it = 0; it < 8; ++it){
        int idx = tid + 256 * it;
        int t = idx >> 4, d4 = (idx & 15) * 4;
        us4 v = *(const us4*)(baseH + (size_t)t * 768 + 512 + h * 64 + d4);
#pragma unroll
        for (int j = 0; j < 4; ++j) Vs[(d4 + j) * 136 + t] = v[j];
    }

    // Q fragments (hi/lo) straight from planes
    short8 qh[2][2], ql[2][2];
#pragma unroll
    for (int sf = 0; sf < 2; ++sf)
#pragma unroll
        for (int ks = 0; ks < 2; ++ks){
            size_t off = (size_t)(w * 32 + sf * 16 + lr) * 768 + h * 64 + ks * 32 + lg * 8;
            qh[sf][ks] = *(const short8*)(baseH + off);
            ql[sf][ks] = *(const short8*)(baseL + off);
        }

    f32x4 dacc[2][8];
#pragma unroll
    for (int i = 0; i < 2; ++i)
#pragma unroll
        for (int j = 0; j < 8; ++j) dacc[i][j] = (f32x4){0.f, 0.f, 0.f, 0.f};

#pragma unroll
    for (int tf = 0; tf < 8; ++tf){
#pragma unroll
        for (int ks = 0; ks < 2; ++ks){
            size_t off = (size_t)(tf * 16 + lr) * 768 + 256 + h * 64 + ks * 32 + lg * 8;
            short8 kh = *(const short8*)(baseH + off);
            short8 kl = *(const short8*)(baseL + off);
#pragma unroll
            for (int sf = 0; sf < 2; ++sf){
                dacc[sf][tf] = __builtin_amdgcn_mfma_f32_16x16x32_bf16(qh[sf][ks], kh, dacc[sf][tf], 0, 0, 0);
                dacc[sf][tf] = __builtin_amdgcn_mfma_f32_16x16x32_bf16(qh[sf][ks], kl, dacc[sf][tf], 0, 0, 0);
                dacc[sf][tf] = __builtin_amdgcn_mfma_f32_16x16x32_bf16(ql[sf][ks], kh, dacc[sf][tf], 0, 0, 0);
            }
        }
    }

    // softmax + write P bf16 + fp32 colsum partials
    float csp[8];
#pragma unroll
    for (int tf = 0; tf < 8; ++tf) csp[tf] = 0.f;
#pragma unroll
    for (int sf = 0; sf < 2; ++sf){
#pragma unroll
        for (int r = 0; r < 4; ++r){
            float m = -INFINITY;
#pragma unroll
            for (int tf = 0; tf < 8; ++tf) m = fmaxf(m, dacc[sf][tf][r]);
            m = fmaxf(m, __shfl_xor(m, 1)); m = fmaxf(m, __shfl_xor(m, 2));
            m = fmaxf(m, __shfl_xor(m, 4)); m = fmaxf(m, __shfl_xor(m, 8));
            float e[8]; float sum = 0.f;
#pragma unroll
            for (int tf = 0; tf < 8; ++tf){
                e[tf] = __expf(0.125f * (dacc[sf][tf][r] - m)); sum += e[tf];
            }
            sum += __shfl_xor(sum, 1); sum += __shfl_xor(sum, 2);
            sum += __shfl_xor(sum, 4); sum += __shfl_xor(sum, 8);
            float inv = 1.f / sum;
            int s = w * 32 + sf * 16 + lg * 4 + r;
#pragma unroll
            for (int tf = 0; tf < 8; ++tf){
                float pv = e[tf] * inv;
                Pm[s * 136 + tf * 16 + lr] = f2bf(pv);
                csp[tf] += pv;
            }
        }
    }
#pragma unroll
    for (int tf = 0; tf < 8; ++tf){
        float v = csp[tf];
        v += __shfl_xor(v, 16); v += __shfl_xor(v, 32);
        if (l < 16) csW[w * 128 + tf * 16 + l] = v;
    }
    __syncthreads();

    // PV: D[d][s] = sum_t V[d][t] P[s][t]
    f32x4 oacc[8];
#pragma unroll
    for (int i = 0; i < 8; ++i) oacc[i] = (f32x4){0.f, 0.f, 0.f, 0.f};
#pragma unroll
    for (int ks = 0; ks < 4; ++ks){
        short8 av = *(const short8*)(Vs + (w * 16 + lr) * 136 + ks * 32 + lg * 8);
#pragma unroll
        for (int sf = 0; sf < 8; ++sf){
            short8 bp = *(const short8*)(Pm + (sf * 16 + lr) * 136 + ks * 32 + lg * 8);
            oacc[sf] = __builtin_amdgcn_mfma_f32_16x16x32_bf16(av, bp, oacc[sf], 0, 0, 0);
        }
    }
    __syncthreads();

    // argmax of colsum (fp32) — first occurrence
    if (tid < 64){
        float v0 = csW[tid] + csW[128 + tid] + csW[256 + tid] + csW[384 + tid];
        float v1 = csW[64 + tid] + csW[192 + tid] + csW[320 + tid] + csW[448 + tid];
        float bv; int bi;
        if (v1 > v0){ bv = v1; bi = 64 + tid; } else { bv = v0; bi = tid; }
#pragma unroll
        for (int msk = 1; msk <= 32; msk <<= 1){
            float ov = __shfl_xor(bv, msk); int oi = __shfl_xor(bi, msk);
            if (ov > bv || (ov == bv && oi < bi)){ bv = ov; bi = oi; }
        }
        if (tid == 0){ int n_g = n0 + n_l; idxA[(n_g * H_ + h) * P_ + p] = bi; }
    }

    // O frags -> Ot[s][d] bf16, then coalesced store over q-cols (hi plane)
#pragma unroll
    for (int sf = 0; sf < 8; ++sf){
        int s = sf * 16 + lr;
#pragma unroll
        for (int r = 0; r < 4; ++r) Ot[s * 72 + w * 16 + lg * 4 + r] = f2bf(oacc[sf][r]);
    }
    __syncthreads();
#pragma unroll
    for (int it = 0; it < 4; ++it){
        int idx = tid + 256 * it;
        int s = idx >> 3, d8 = (idx & 7) * 8;
        *(short8*)(baseH + (size_t)s * 768 + h * 64 + d8) = *(const short8*)(Ot + s * 72 + d8);
    }
}

// ---------------------------------------------------------------------------
__global__ void bn_stats(const float* __restrict__ wpvT,
                         const float* __restrict__ gamma,
                         const float* __restrict__ beta,
                         float* __restrict__ aArr, float* __restrict__ bArr)
{
    int i = blockIdx.x * blockDim.x + threadIdx.x;
    if (i >= P_ * C_) return;
    int p = i / C_, c = i % C_;
    const float* basep = wpvT + (size_t)p * N_ * C_ + c;
    float su = 0.f, s2 = 0.f;
    for (int n = 0; n < N_; ++n){
        float v = basep[n * C_];
        su += v; s2 += v * v;
    }
    float mean = su * (1.f / N_);
    float var = s2 * (1.f / N_) - mean * mean;
    float rstd = rsqrtf(var + 1e-5f);
    float a = gamma[i] * rstd;
    aArr[i] = a;
    bArr[i] = beta[i] - mean * a;
}

// pf[m][c] = bf16(wpvT[m][c]*a + b), m = p*32+n
__global__ __launch_bounds__(256) void pf_kernel(const float* __restrict__ wpvT,
                                                 const float* __restrict__ aArr,
                                                 const float* __restrict__ bArr,
                                                 unsigned short* __restrict__ pfb){
    int m = blockIdx.x, c = threadIdx.x;
    int p = m >> 5;
    float v = wpvT[(size_t)m * 256 + c];
    pfb[(size_t)m * 256 + c] = f2bf(v * aArr[p * 256 + c] + bArr[p * 256 + c]);
}

// cls GEMM: cls[n*16+p][k] = sum_c pf[p*32+n][c] * fcT[k][c]; 1-term bf16
__global__ __launch_bounds__(256) void gemmc(const unsigned short* __restrict__ pfb,
                                             const unsigned short* __restrict__ fcT,
                                             float* __restrict__ cls){
    __shared__ unsigned short sm[2 * 128 * 72];
    unsigned short* AhL = sm;
    unsigned short* BhL = sm + 128 * 72;

    const int tid = threadIdx.x;
    const int w = tid >> 6, l = tid & 63;
    const int lr = l & 15, lg = l >> 4;
    const int ws0 = (w & 1) * 64, wo0 = (w >> 1) * 64;
    const int o0 = blockIdx.x * 128;
    const int m0 = blockIdx.y * 128;

    f32x4 acc[4][4];
#pragma unroll
    for (int i = 0; i < 4; ++i)
#pragma unroll
        for (int j = 0; j < 4; ++j) acc[i][j] = (f32x4){0.f, 0.f, 0.f, 0.f};

    for (int k0 = 0; k0 < 256; k0 += 64){
#pragma unroll
        for (int it = 0; it < 4; ++it){
            int idx = tid + 256 * it;
            int s = idx >> 3, c8 = (idx & 7) * 8;
            *(short8*)(AhL + s * 72 + c8) = *(const short8*)(pfb + (size_t)(m0 + s) * 256 + k0 + c8);
            *(short8*)(BhL + s * 72 + c8) = *(const short8*)(fcT + (size_t)(o0 + s) * 256 + k0 + c8);
        }
        __syncthreads();
#pragma unroll
        for (int ks = 0; ks < 2; ++ks){
            short8 ah[4];
#pragma unroll
            for (int sf = 0; sf < 4; ++sf)
                ah[sf] = *(const short8*)(AhL + (ws0 + sf * 16 + lr) * 72 + ks * 32 + lg * 8);
#pragma unroll
            for (int of = 0; of < 4; ++of){
                short8 bh = *(const short8*)(BhL + (wo0 + of * 16 + lr) * 72 + ks * 32 + lg * 8);
#pragma unroll
                for (int sf = 0; sf < 4; ++sf)
                    acc[sf][of] = __builtin_amdgcn_mfma_f32_16x16x32_bf16(ah[sf], bh, acc[sf][of], 0, 0, 0);
            }
        }
        __syncthreads();
    }
#pragma unroll
    for (int sf = 0; sf < 4; ++sf)
#pragma unroll
        for (int of = 0; of < 4; ++of){
            int oc = o0 + wo0 + of * 16 + lr;
            if (oc < CLS_){
#pragma unroll
                for (int r = 0; r < 4; ++r){
                    int m = m0 + ws0 + sf * 16 + lg * 4 + r;
                    int n = m & 31, p = m >> 5;
                    cls[((size_t)n * 16 + p) * CLS_ + oc] = acc[sf][of][r];
                }
            }
        }
}

__global__ void sel_kernel(const float* __restrict__ t_f,
                           const int* __restrict__ idxArr,
                           float* __restrict__ selT)
{
    const int np = blockIdx.x;
    const int n = np >> 4, p = np & 15;
    const int c = threadIdx.x;
    float acc = 0.f;
#pragma unroll
    for (int h = 0; h < H_; ++h){
        int s = idxArr[(n * H_ + h) * P_ + p];
        acc += t_f[((size_t)np * C_ + c) * S_ + s];
    }
    selT[((size_t)p * N_ + n) * C_ + c] = acc;
}

// ---------------------------------------------------------------------------
extern "C" void kernel_launch(void* const* d_in, const int* in_sizes, int n_in,
                              void* d_out, int out_size, void* d_ws, size_t ws_size,
                              hipStream_t stream)
{
    const float* t_f     = (const float*)d_in[0];
    const float* t_s     = (const float*)d_in[1];
    const float* t_l     = (const float*)d_in[2];
    const float* decay_w = (const float*)d_in[3];
    const float* qkv_w   = (const float*)d_in[4];
    const float* out_w   = (const float*)d_in[5];
    const float* gamma   = (const float*)d_in[6];
    const float* beta    = (const float*)d_in[7];
    const float* fc      = (const float*)d_in[8];
    float* out = (float*)d_out;

    // ---- ws layout: converted weights at head, then chunked activations ----
    const size_t WD = 3145728, WQ = 3145728, WO = 1048576;
    char* basep = (char*)d_ws;
    unsigned short* wdh = (unsigned short*)basep;
    unsigned short* wdl = wdh + WD;
    unsigned short* wqh = wdl + WD;
    unsigned short* wql = wqh + WQ;
    unsigned short* woh = wql + WQ;
    unsigned short* fcT = woh + WO;            // 3072*256
    unsigned short* pfb = fcT + 3072 * 256;    // 512*256
    float* aArr = (float*)(pfb + 512 * 256);
    float* bArr = aArr + P_ * C_;
    int* idxA = (int*)(bArr + P_ * C_);
    char* big = (char*)(idxA + N_ * H_ * P_);
    size_t head = (size_t)(big - basep);
    size_t avail = (ws_size > head) ? (ws_size - head) : 0;
    const size_t per_n = (size_t)16 * 128 * (768 + 256 + 768) * 2 * 2;  // hi+lo bf16
    int cn = (int)(avail / per_n);
    if (cn < 1) cn = 1;
    if (cn > N_) cn = N_;
    int nch = (N_ + cn - 1) / cn;
    cn = (N_ + nch - 1) / nch;

    unsigned short* xH = (unsigned short*)big;                 // cn*16*128*768
    unsigned short* xL = xH + (size_t)cn * 16 * 128 * 768;
    unsigned short* tH = xL + (size_t)cn * 16 * 128 * 768;     // cn*16*128*256
    unsigned short* tL = tH + (size_t)cn * 16 * 128 * 256;
    unsigned short* qH = tL + (size_t)cn * 16 * 128 * 256;     // cn*16*128*768
    unsigned short* qL = qH + (size_t)cn * 16 * 128 * 768;

    float* cls  = out;
    float* wpvT = out + (size_t)N_ * P_ * CLS_;
    float* selT = wpvT + (size_t)P_ * N_ * C_;

    wsplit<<<2048, 256, 0, stream>>>(decay_w, qkv_w, out_w, wdh, wdl, wqh, wql, woh);
    fct_kernel<<<12, 256, 0, stream>>>(fc, fcT);

    for (int n0 = 0; n0 < N_; n0 += cn){
        int c = (N_ - n0 < cn) ? (N_ - n0) : cn;
        int npg = c * 16;
        xT_kernel<<<dim3(npg, 3), 256, 0, stream>>>(t_f, t_s, t_l, xH, xL, n0);
        gemm3<768, 768, 256, 0, 256><<<dim3(2, npg), 256, 0, stream>>>(
            xH, xL, wdh, wdl, nullptr, nullptr, tH, tL, nullptr, n0);
        gemm3<256, 256, 768, 1, 768><<<dim3(6, npg), 256, 0, stream>>>(
            tH, tL, wqh, wql, nullptr, nullptr, qH, qL, nullptr, n0);
        attn3<<<dim3(c * 64), 256, 0, stream>>>(qH, qL, idxA, n0);
        gemm3<256, 768, 256, 2, 256><<<dim3(2, npg), 256, 0, stream>>>(
            qH, qH, woh, woh, tH, tL, nullptr, nullptr, wpvT, n0);
    }
    bn_stats<<<(P_ * C_ + 255) / 256, 256, 0, stream>>>(wpvT, gamma, beta, aArr, bArr);
    pf_kernel<<<512, 256, 0, stream>>>(wpvT, aArr, bArr, pfb);
    gemmc<<<dim3(24, 4), 256, 0, stream>>>(pfb, fcT, cls);
    sel_kernel<<<N_ * P_, 256, 0, stream>>>(t_f, idxA, selT);
}

// Round 5
// 541.089 us; speedup vs baseline: 2.8053x; 1.0614x over previous
//
#include <hip/hip_runtime.h>
#include <math.h>

#define N_ 32
#define P_ 16
#define C_ 256
#define S_ 128
#define H_ 4
#define CLS_ 3000

typedef __attribute__((ext_vector_type(4))) float f4v;
typedef __attribute__((ext_vector_type(4))) float f32x4;
typedef __attribute__((ext_vector_type(8))) short short8;
typedef __attribute__((ext_vector_type(4))) unsigned short us4;

__device__ __forceinline__ unsigned short f2bf(float x){
    unsigned u = __float_as_uint(x);
    u += 0x7fffu + ((u >> 16) & 1u);
    return (unsigned short)(u >> 16);
}
__device__ __forceinline__ float bf2f(unsigned short h){
    return __uint_as_float(((unsigned)h) << 16);
}

typedef __attribute__((address_space(1))) const unsigned int gu32_t;
typedef __attribute__((address_space(3))) unsigned int lu32_t;
__device__ __forceinline__ void gload16(const void* g, void* l){
    __builtin_amdgcn_global_load_lds((gu32_t*)g, (lu32_t*)l, 16, 0, 0);
}

// ---------------------------------------------------------------------------
// Split weights fp32 -> bf16 hi/lo (decay_w, qkv_w) and hi-only (out_w)
// ---------------------------------------------------------------------------
__global__ void wsplit(const float* __restrict__ dw, const float* __restrict__ qw,
                       const float* __restrict__ ow,
                       unsigned short* __restrict__ wdh, unsigned short* __restrict__ wdl,
                       unsigned short* __restrict__ wqh, unsigned short* __restrict__ wql,
                       unsigned short* __restrict__ woh){
    int i = blockIdx.x * 256 + threadIdx.x;
    int stride = gridDim.x * 256;
    for (; i < 3145728; i += stride){
        float a = dw[i]; unsigned short h = f2bf(a);
        wdh[i] = h; wdl[i] = f2bf(a - bf2f(h));
        float b = qw[i]; unsigned short h2 = f2bf(b);
        wqh[i] = h2; wql[i] = f2bf(b - bf2f(h2));
        if (i < 1048576) woh[i] = f2bf(ow[i]);
    }
}

// fc [256][3000] fp32 -> fcT [3072][256] bf16 (rows >= 3000 zeroed)
__global__ __launch_bounds__(256) void fct_kernel(const float* __restrict__ fc,
                                                  unsigned short* __restrict__ fcT){
    int n = blockIdx.x * 256 + threadIdx.x;   // 0..3071
    if (n < CLS_){
        for (int c = 0; c < 256; ++c) fcT[(size_t)n * 256 + c] = f2bf(fc[(size_t)c * CLS_ + n]);
    } else {
        for (int c = 0; c < 256; ++c) fcT[(size_t)n * 256 + c] = 0;
    }
}

// ---------------------------------------------------------------------------
// LDS-tiled transpose: x{H,L}[np_l][s][tsel*256+c] = split(t_x[np_g][c][s])
// 4 passes of 64-c subtiles; fp32 LDS pitch 132 (conflict-free both phases).
// ---------------------------------------------------------------------------
__global__ __launch_bounds__(256) void xT_kernel(
    const float* __restrict__ t_f, const float* __restrict__ t_s,
    const float* __restrict__ t_l,
    unsigned short* __restrict__ xH, unsigned short* __restrict__ xL, int n0){
    __shared__ float T[64 * 132];
    const int np_l = blockIdx.x, tsel = blockIdx.y;
    const float* src = (tsel == 0) ? t_f : ((tsel == 1) ? t_s : t_l);
    const size_t np_g = (size_t)(n0 * 16) + np_l;
    const float* sbase = src + np_g * 256 * 128;
    const size_t dbase = (size_t)np_l * 128 * 768 + tsel * 256;
    const int tid = threadIdx.x;
    const int so = tid & 127, ch = tid >> 7;   // write phase: row s, c-half

    for (int cp = 0; cp < 4; ++cp){
        const int c0 = cp * 64;
        // read 64c x 128s fp32, coalesced f4
#pragma unroll
        for (int it = 0; it < 8; ++it){
            int f = tid + 256 * it;
            int c = f >> 5, s4 = (f & 31) << 2;
            *(f4v*)(T + c * 132 + s4) = *(const f4v*)(sbase + (size_t)(c0 + c) * 128 + s4);
        }
        __syncthreads();
        // write phase: thread -> (s=so, 32 c at ch*32)
        short8 Hh[4], Ll[4];
#pragma unroll
        for (int c8 = 0; c8 < 4; ++c8){
#pragma unroll
            for (int j = 0; j < 8; ++j){
                float v = T[(ch * 32 + c8 * 8 + j) * 132 + so];
                unsigned short hh = f2bf(v);
                Hh[c8][j] = (short)hh;
                Ll[c8][j] = (short)f2bf(v - bf2f(hh));
            }
        }
        size_t dr = dbase + (size_t)so * 768 + c0 + ch * 32;
#pragma unroll
        for (int c8 = 0; c8 < 4; ++c8){
            *(short8*)(xH + dr + c8 * 8) = Hh[c8];
            *(short8*)(xL + dr + c8 * 8) = Ll[c8];
        }
        __syncthreads();
    }
}

// ---------------------------------------------------------------------------
// Split-bf16 MFMA GEMM:  D[s][o] = sum_k A[s][k] * W[o][k]
// A: bf16 hi/lo planes [np_l*128+s][APITCH]; W: pre-split bf16 [P][ND][KEXT].
// Staging: global_load_lds(16) into linear [128][64]-short tiles, 16B-chunk
// XOR-swizzled by (row&7) on the SOURCE address; frag reads apply same XOR.
// MODE 0/1 (3-term): write hi/lo bf16 planes; MODE 2 (1-term): wpv epilogue.
// ---------------------------------------------------------------------------
template<int KEXT, int APITCH, int ND, int MODE, int OPITCH>
__global__ __launch_bounds__(256) void gemm3(
    const unsigned short* __restrict__ Ah_g, const unsigned short* __restrict__ Al_g,
    const unsigned short* __restrict__ Whi, const unsigned short* __restrict__ Wlo,
    const unsigned short* __restrict__ resH, const unsigned short* __restrict__ resL,
    unsigned short* __restrict__ outH, unsigned short* __restrict__ outL,
    float* __restrict__ outF, int n0)
{
    constexpr int T3 = (MODE == 2) ? 0 : 1;
    __shared__ unsigned short sm[(T3 ? 4 : 2) * 128 * 64];
    unsigned short* AhL = sm;
    unsigned short* BhL = sm + 8192;
    unsigned short* AlL = T3 ? (sm + 16384) : sm;
    unsigned short* BlL = T3 ? (sm + 24576) : sm;
    __shared__ float cmax[2][2][64];

    const int tid = threadIdx.x;
    const int w = tid >> 6, l = tid & 63;
    const int lr = l & 15, lg = l >> 4;
    const int ws0 = (w & 1) * 64, wo0 = (w >> 1) * 64;
    const int o0 = blockIdx.x * 128;
    const int np_l = blockIdx.y;
    const int p = np_l & 15;
    const size_t aBase = (size_t)np_l * 128 * APITCH;
    const unsigned short* Wp_h = Whi + ((size_t)p * ND + o0) * KEXT;
    const unsigned short* Wp_l = T3 ? (Wlo + ((size_t)p * ND + o0) * KEXT) : Wp_h;

    f32x4 acc[4][4];
#pragma unroll
    for (int i = 0; i < 4; ++i)
#pragma unroll
        for (int j = 0; j < 4; ++j) acc[i][j] = (f32x4){0.f, 0.f, 0.f, 0.f};

    for (int k0 = 0; k0 < KEXT; k0 += 64){
        // --- async staging: 1024B per wave-inst; lane lin = slot*64 + l ---
#pragma unroll
        for (int it = 0; it < 4; ++it){
            int slot = w * 4 + it;
            int lin = slot * 64 + l;
            int row = lin >> 3, chnk = lin & 7;
            int sk = ((chnk ^ (row & 7)) << 3);
            unsigned short* ldst = sm + slot * 512;  // shorts; +8192*plane below
            const unsigned short* ga = Ah_g + aBase + (size_t)row * APITCH + k0 + sk;
            gload16(ga, ldst);
            const unsigned short* gb = Wp_h + (size_t)row * KEXT + k0 + sk;
            gload16(gb, ldst + 8192);
            if (T3){
                gload16(Al_g + aBase + (size_t)row * APITCH + k0 + sk, ldst + 16384);
                gload16(Wp_l + (size_t)row * KEXT + k0 + sk, ldst + 24576);
            }
        }
        __syncthreads();
#pragma unroll
        for (int ks = 0; ks < 2; ++ks){
            short8 ah[4], al[4];
#pragma unroll
            for (int sf = 0; sf < 4; ++sf){
                int row = ws0 + sf * 16 + lr;
                int cof = ((ks * 4 + lg) ^ (row & 7)) << 3;
                ah[sf] = *(const short8*)(AhL + row * 64 + cof);
                if (T3) al[sf] = *(const short8*)(AlL + row * 64 + cof);
            }
#pragma unroll
            for (int of = 0; of < 4; ++of){
                int row = wo0 + of * 16 + lr;
                int cof = ((ks * 4 + lg) ^ (row & 7)) << 3;
                short8 bh = *(const short8*)(BhL + row * 64 + cof);
                short8 bl = bh;
                if (T3) bl = *(const short8*)(BlL + row * 64 + cof);
#pragma unroll
                for (int sf = 0; sf < 4; ++sf){
                    acc[sf][of] = __builtin_amdgcn_mfma_f32_16x16x32_bf16(ah[sf], bh, acc[sf][of], 0, 0, 0);
                    if (T3){
                        acc[sf][of] = __builtin_amdgcn_mfma_f32_16x16x32_bf16(ah[sf], bl, acc[sf][of], 0, 0, 0);
                        acc[sf][of] = __builtin_amdgcn_mfma_f32_16x16x32_bf16(al[sf], bh, acc[sf][of], 0, 0, 0);
                    }
                }
            }
        }
        __syncthreads();
    }

    if (MODE != 2){
#pragma unroll
        for (int sf = 0; sf < 4; ++sf)
#pragma unroll
            for (int of = 0; of < 4; ++of){
                int oc = o0 + wo0 + of * 16 + lr;
#pragma unroll
                for (int r = 0; r < 4; ++r){
                    int s = ws0 + sf * 16 + lg * 4 + r;
                    size_t di = (size_t)np_l * 128 * OPITCH + (size_t)s * OPITCH + oc;
                    float v = acc[sf][of][r];
                    unsigned short hh = f2bf(v);
                    outH[di] = hh;
                    outL[di] = f2bf(v - bf2f(hh));
                }
            }
    } else {
        const int n_g = n0 + (np_l >> 4);
#pragma unroll
        for (int of = 0; of < 4; ++of){
            int oc = o0 + wo0 + of * 16 + lr;
            float m = -INFINITY;
#pragma unroll
            for (int sf = 0; sf < 4; ++sf){
#pragma unroll
                for (int r = 0; r < 4; ++r){
                    int s = ws0 + sf * 16 + lg * 4 + r;
                    size_t ri = (size_t)np_l * 128 * 256 + (size_t)s * 256 + oc;
                    float v = acc[sf][of][r] + bf2f(resH[ri]) + bf2f(resL[ri]);
                    m = fmaxf(m, v);
                }
            }
            m = fmaxf(m, __shfl_xor(m, 16));
            m = fmaxf(m, __shfl_xor(m, 32));
            if (l < 16) cmax[w >> 1][w & 1][of * 16 + l] = m;
        }
        __syncthreads();
        if (tid < 128){
            int oh = tid >> 6, col = tid & 63;
            float v = fmaxf(cmax[oh][0][col], cmax[oh][1][col]);
            outF[((size_t)p * N_ + n_g) * C_ + o0 + oh * 64 + col] = v;
        }
    }
}

// ---------------------------------------------------------------------------
// Attention per (n,h,p): 3-term split QK^T MFMA (bf16 plane inputs),
// fp32 softmax+colsum (argmax), bf16 PV MFMA; O (bf16 hi) overwrites q-cols.
// ---------------------------------------------------------------------------
__global__ __launch_bounds__(256) void attn3(unsigned short* __restrict__ qH,
                                             const unsigned short* __restrict__ qL,
                                             int* __restrict__ idxA, int n0){
    __shared__ char smraw[17408 + 34816 + 2048];
    unsigned short* Vs = (unsigned short*)smraw;             // [64][136] bf16
    unsigned short* Pm = (unsigned short*)(smraw + 17408);   // [128][136] bf16
    float* csW = (float*)(smraw + 17408 + 34816);            // [4][128]
    unsigned short* Ot = (unsigned short*)smraw;             // [128][72] bf16 (alias)

    const int b = blockIdx.x;
    const int n_l = b >> 6, h = (b >> 4) & 3, p = b & 15;
    const int np_l = n_l * 16 + p;
    const int tid = threadIdx.x, w = tid >> 6, l = tid & 63;
    const int lr = l & 15, lg = l >> 4;
    unsigned short* baseH = qH + (size_t)np_l * 128 * 768;
    const unsigned short* baseL = qL + (size_t)np_l * 128 * 768;

    // stage V: bf16 [t][d] -> Vs[d][t]
#pragma unroll
    for (int it = 0; it < 8; ++it){
        int idx = tid + 256 * it;
        int t = idx >> 4, d4 = (idx & 15) * 4;
        us4 v = *(const us4*)(baseH + (size_t)t * 768 + 512 + h * 64 + d4);
#pragma unroll
        for (int j = 0; j < 4; ++j) Vs[(d4 + j) * 136 + t] = v[j];
    }

    // Q fragments (hi/lo) straight from planes
    short8 qh[2][2], ql[2][2];
#pragma unroll
    for (int sf = 0; sf < 2; ++sf)
#pragma unroll
        for (int ks = 0; ks < 2; ++ks){
            size_t off = (size_t)(w * 32 + sf * 16 + lr) * 768 + h * 64 + ks * 32 + lg * 8;
            qh[sf][ks] = *(const short8*)(baseH + off);
            ql[sf][ks] = *(const short8*)(baseL + off);
        }

    f32x4 dacc[2][8];
#pragma unroll
    for (int i = 0; i < 2; ++i)
#pragma unroll
        for (int j = 0; j < 8; ++j) dacc[i][j] = (f32x4){0.f, 0.f, 0.f, 0.f};

#pragma unroll
    for (int tf = 0; tf < 8; ++tf){
#pragma unroll
        for (int ks = 0; ks < 2; ++ks){
            size_t off = (size_t)(tf * 16 + lr) * 768 + 256 + h * 64 + ks * 32 + lg * 8;
            short8 kh = *(const short8*)(baseH + off);
            short8 kl = *(const short8*)(baseL + off);
#pragma unroll
            for (int sf = 0; sf < 2; ++sf){
                dacc[sf][tf] = __builtin_amdgcn_mfma_f32_16x16x32_bf16(qh[sf][ks], kh, dacc[sf][tf], 0, 0, 0);
                dacc[sf][tf] = __builtin_amdgcn_mfma_f32_16x16x32_bf16(qh[sf][ks], kl, dacc[sf][tf], 0, 0, 0);
                dacc[sf][tf] = __builtin_amdgcn_mfma_f32_16x16x32_bf16(ql[sf][ks], kh, dacc[sf][tf], 0, 0, 0);
            }
        }
    }

    // softmax + write P bf16 + fp32 colsum partials
    float csp[8];
#pragma unroll
    for (int tf = 0; tf < 8; ++tf) csp[tf] = 0.f;
#pragma unroll
    for (int sf = 0; sf < 2; ++sf){
#pragma unroll
        for (int r = 0; r < 4; ++r){
            float m = -INFINITY;
#pragma unroll
            for (int tf = 0; tf < 8; ++tf) m = fmaxf(m, dacc[sf][tf][r]);
            m = fmaxf(m, __shfl_xor(m, 1)); m = fmaxf(m, __shfl_xor(m, 2));
            m = fmaxf(m, __shfl_xor(m, 4)); m = fmaxf(m, __shfl_xor(m, 8));
            float e[8]; float sum = 0.f;
#pragma unroll
            for (int tf = 0; tf < 8; ++tf){
                e[tf] = __expf(0.125f * (dacc[sf][tf][r] - m)); sum += e[tf];
            }
            sum += __shfl_xor(sum, 1); sum += __shfl_xor(sum, 2);
            sum += __shfl_xor(sum, 4); sum += __shfl_xor(sum, 8);
            float inv = 1.f / sum;
            int s = w * 32 + sf * 16 + lg * 4 + r;
#pragma unroll
            for (int tf = 0; tf < 8; ++tf){
                float pv = e[tf] * inv;
                Pm[s * 136 + tf * 16 + lr] = f2bf(pv);
                csp[tf] += pv;
            }
        }
    }
#pragma unroll
    for (int tf = 0; tf < 8; ++tf){
        float v = csp[tf];
        v += __shfl_xor(v, 16); v += __shfl_xor(v, 32);
        if (l < 16) csW[w * 128 + tf * 16 + l] = v;
    }
    __syncthreads();

    // PV: D[d][s] = sum_t V[d][t] P[s][t]
    f32x4 oacc[8];
#pragma unroll
    for (int i = 0; i < 8; ++i) oacc[i] = (f32x4){0.f, 0.f, 0.f, 0.f};
#pragma unroll
    for (int ks = 0; ks < 4; ++ks){
        short8 av = *(const short8*)(Vs + (w * 16 + lr) * 136 + ks * 32 + lg * 8);
#pragma unroll
        for (int sf = 0; sf < 8; ++sf){
            short8 bp = *(const short8*)(Pm + (sf * 16 + lr) * 136 + ks * 32 + lg * 8);
            oacc[sf] = __builtin_amdgcn_mfma_f32_16x16x32_bf16(av, bp, oacc[sf], 0, 0, 0);
        }
    }
    __syncthreads();

    // argmax of colsum (fp32) — first occurrence
    if (tid < 64){
        float v0 = csW[tid] + csW[128 + tid] + csW[256 + tid] + csW[384 + tid];
        float v1 = csW[64 + tid] + csW[192 + tid] + csW[320 + tid] + csW[448 + tid];
        float bv; int bi;
        if (v1 > v0){ bv = v1; bi = 64 + tid; } else { bv = v0; bi = tid; }
#pragma unroll
        for (int msk = 1; msk <= 32; msk <<= 1){
            float ov = __shfl_xor(bv, msk); int oi = __shfl_xor(bi, msk);
            if (ov > bv || (ov == bv && oi < bi)){ bv = ov; bi = oi; }
        }
        if (tid == 0){ int n_g = n0 + n_l; idxA[(n_g * H_ + h) * P_ + p] = bi; }
    }

    // O frags -> Ot[s][d] bf16, then coalesced store over q-cols (hi plane)
#pragma unroll
    for (int sf = 0; sf < 8; ++sf){
        int s = sf * 16 + lr;
#pragma unroll
        for (int r = 0; r < 4; ++r) Ot[s * 72 + w * 16 + lg * 4 + r] = f2bf(oacc[sf][r]);
    }
    __syncthreads();
#pragma unroll
    for (int it = 0; it < 4; ++it){
        int idx = tid + 256 * it;
        int s = idx >> 3, d8 = (idx & 7) * 8;
        *(short8*)(baseH + (size_t)s * 768 + h * 64 + d8) = *(const short8*)(Ot + s * 72 + d8);
    }
}

// ---------------------------------------------------------------------------
__global__ void bn_stats(const float* __restrict__ wpvT,
                         const float* __restrict__ gamma,
                         const float* __restrict__ beta,
                         float* __restrict__ aArr, float* __restrict__ bArr)
{
    int i = blockIdx.x * blockDim.x + threadIdx.x;
    if (i >= P_ * C_) return;
    int p = i / C_, c = i % C_;
    const float* basep = wpvT + (size_t)p * N_ * C_ + c;
    float su = 0.f, s2 = 0.f;
    for (int n = 0; n < N_; ++n){
        float v = basep[n * C_];
        su += v; s2 += v * v;
    }
    float mean = su * (1.f / N_);
    float var = s2 * (1.f / N_) - mean * mean;
    float rstd = rsqrtf(var + 1e-5f);
    float a = gamma[i] * rstd;
    aArr[i] = a;
    bArr[i] = beta[i] - mean * a;
}

// pf[m][c] = bf16(wpvT[m][c]*a + b), m = p*32+n
__global__ __launch_bounds__(256) void pf_kernel(const float* __restrict__ wpvT,
                                                 const float* __restrict__ aArr,
                                                 const float* __restrict__ bArr,
                                                 unsigned short* __restrict__ pfb){
    int m = blockIdx.x, c = threadIdx.x;
    int p = m >> 5;
    float v = wpvT[(size_t)m * 256 + c];
    pfb[(size_t)m * 256 + c] = f2bf(v * aArr[p * 256 + c] + bArr[p * 256 + c]);
}

// cls GEMM: cls[n*16+p][k] = sum_c pf[p*32+n][c] * fcT[k][c]; 1-term bf16
__global__ __launch_bounds__(256) void gemmc(const unsigned short* __restrict__ pfb,
                                             const unsigned short* __restrict__ fcT,
                                             float* __restrict__ cls){
    __shared__ unsigned short sm[2 * 128 * 72];
    unsigned short* AhL = sm;
    unsigned short* BhL = sm + 128 * 72;

    const int tid = threadIdx.x;
    const int w = tid >> 6, l = tid & 63;
    const int lr = l & 15, lg = l >> 4;
    const int ws0 = (w & 1) * 64, wo0 = (w >> 1) * 64;
    const int o0 = blockIdx.x * 128;
    const int m0 = blockIdx.y * 128;

    f32x4 acc[4][4];
#pragma unroll
    for (int i = 0; i < 4; ++i)
#pragma unroll
        for (int j = 0; j < 4; ++j) acc[i][j] = (f32x4){0.f, 0.f, 0.f, 0.f};

    for (int k0 = 0; k0 < 256; k0 += 64){
#pragma unroll
        for (int it = 0; it < 4; ++it){
            int idx = tid + 256 * it;
            int s = idx >> 3, c8 = (idx & 7) * 8;
            *(short8*)(AhL + s * 72 + c8) = *(const short8*)(pfb + (size_t)(m0 + s) * 256 + k0 + c8);
            *(short8*)(BhL + s * 72 + c8) = *(const short8*)(fcT + (size_t)(o0 + s) * 256 + k0 + c8);
        }
        __syncthreads();
#pragma unroll
        for (int ks = 0; ks < 2; ++ks){
            short8 ah[4];
#pragma unroll
            for (int sf = 0; sf < 4; ++sf)
                ah[sf] = *(const short8*)(AhL + (ws0 + sf * 16 + lr) * 72 + ks * 32 + lg * 8);
#pragma unroll
            for (int of = 0; of < 4; ++of){
                short8 bh = *(const short8*)(BhL + (wo0 + of * 16 + lr) * 72 + ks * 32 + lg * 8);
#pragma unroll
                for (int sf = 0; sf < 4; ++sf)
                    acc[sf][of] = __builtin_amdgcn_mfma_f32_16x16x32_bf16(ah[sf], bh, acc[sf][of], 0, 0, 0);
            }
        }
        __syncthreads();
    }
#pragma unroll
    for (int sf = 0; sf < 4; ++sf)
#pragma unroll
        for (int of = 0; of < 4; ++of){
            int oc = o0 + wo0 + of * 16 + lr;
            if (oc < CLS_){
#pragma unroll
                for (int r = 0; r < 4; ++r){
                    int m = m0 + ws0 + sf * 16 + lg * 4 + r;
                    int n = m & 31, p = m >> 5;
                    cls[((size_t)n * 16 + p) * CLS_ + oc] = acc[sf][of][r];
                }
            }
        }
}

__global__ void sel_kernel(const float* __restrict__ t_f,
                           const int* __restrict__ idxArr,
                           float* __restrict__ selT)
{
    const int np = blockIdx.x;
    const int n = np >> 4, p = np & 15;
    const int c = threadIdx.x;
    float acc = 0.f;
#pragma unroll
    for (int h = 0; h < H_; ++h){
        int s = idxArr[(n * H_ + h) * P_ + p];
        acc += t_f[((size_t)np * C_ + c) * S_ + s];
    }
    selT[((size_t)p * N_ + n) * C_ + c] = acc;
}

// ---------------------------------------------------------------------------
extern "C" void kernel_launch(void* const* d_in, const int* in_sizes, int n_in,
                              void* d_out, int out_size, void* d_ws, size_t ws_size,
                              hipStream_t stream)
{
    const float* t_f     = (const float*)d_in[0];
    const float* t_s     = (const float*)d_in[1];
    const float* t_l     = (const float*)d_in[2];
    const float* decay_w = (const float*)d_in[3];
    const float* qkv_w   = (const float*)d_in[4];
    const float* out_w   = (const float*)d_in[5];
    const float* gamma   = (const float*)d_in[6];
    const float* beta    = (const float*)d_in[7];
    const float* fc      = (const float*)d_in[8];
    float* out = (float*)d_out;

    // ---- ws layout: converted weights at head, then chunked activations ----
    const size_t WD = 3145728, WQ = 3145728, WO = 1048576;
    char* basep = (char*)d_ws;
    unsigned short* wdh = (unsigned short*)basep;
    unsigned short* wdl = wdh + WD;
    unsigned short* wqh = wdl + WD;
    unsigned short* wql = wqh + WQ;
    unsigned short* woh = wql + WQ;
    unsigned short* fcT = woh + WO;            // 3072*256
    unsigned short* pfb = fcT + 3072 * 256;    // 512*256
    float* aArr = (float*)(pfb + 512 * 256);
    float* bArr = aArr + P_ * C_;
    int* idxA = (int*)(bArr + P_ * C_);
    char* big = (char*)(idxA + N_ * H_ * P_);
    size_t head = (size_t)(big - basep);
    size_t avail = (ws_size > head) ? (ws_size - head) : 0;
    const size_t per_n = (size_t)16 * 128 * (768 + 256 + 768) * 2 * 2;  // hi+lo bf16
    int cn = (int)(avail / per_n);
    if (cn < 1) cn = 1;
    if (cn > N_) cn = N_;
    int nch = (N_ + cn - 1) / cn;
    cn = (N_ + nch - 1) / nch;

    unsigned short* xH = (unsigned short*)big;                 // cn*16*128*768
    unsigned short* xL = xH + (size_t)cn * 16 * 128 * 768;
    unsigned short* tH = xL + (size_t)cn * 16 * 128 * 768;     // cn*16*128*256
    unsigned short* tL = tH + (size_t)cn * 16 * 128 * 256;
    unsigned short* qH = tL + (size_t)cn * 16 * 128 * 256;     // cn*16*128*768
    unsigned short* qL = qH + (size_t)cn * 16 * 128 * 768;

    float* cls  = out;
    float* wpvT = out + (size_t)N_ * P_ * CLS_;
    float* selT = wpvT + (size_t)P_ * N_ * C_;

    wsplit<<<2048, 256, 0, stream>>>(decay_w, qkv_w, out_w, wdh, wdl, wqh, wql, woh);
    fct_kernel<<<12, 256, 0, stream>>>(fc, fcT);

    for (int n0 = 0; n0 < N_; n0 += cn){
        int c = (N_ - n0 < cn) ? (N_ - n0) : cn;
        int npg = c * 16;
        xT_kernel<<<dim3(npg, 3), 256, 0, stream>>>(t_f, t_s, t_l, xH, xL, n0);
        gemm3<768, 768, 256, 0, 256><<<dim3(2, npg), 256, 0, stream>>>(
            xH, xL, wdh, wdl, nullptr, nullptr, tH, tL, nullptr, n0);
        gemm3<256, 256, 768, 1, 768><<<dim3(6, npg), 256, 0, stream>>>(
            tH, tL, wqh, wql, nullptr, nullptr, qH, qL, nullptr, n0);
        attn3<<<dim3(c * 64), 256, 0, stream>>>(qH, qL, idxA, n0);
        gemm3<256, 768, 256, 2, 256><<<dim3(2, npg), 256, 0, stream>>>(
            qH, qH, woh, woh, tH, tL, nullptr, nullptr, wpvT, n0);
    }
    bn_stats<<<(P_ * C_ + 255) / 256, 256, 0, stream>>>(wpvT, gamma, beta, aArr, bArr);
    pf_kernel<<<512, 256, 0, stream>>>(wpvT, aArr, bArr, pfb);
    gemmc<<<dim3(24, 4), 256, 0, stream>>>(pfb, fcT, cls);
    sel_kernel<<<N_ * P_, 256, 0, stream>>>(t_f, idxA, selT);
}